// Round 13
// baseline (220.687 us; speedup 1.0000x reference)
//
#include <hip/hip_runtime.h>
#include <math.h>

#define N_NODES 100000
#define N_EDGES 1600000
#define D 128
#define NEG_SLOPE_F 0.2f
#define BK 32                 // nodes per bucket
#define NB3 3125              // N_NODES / 32 (exact)
#define ECAP 1024             // slab capacity per bucket (avg 512, max ~610)
#define BEPB 16384            // edges per block, bin branch
#define NBINB 98              // ceil(N_EDGES / BEPB)
#define NGEMM 1563            // ceil(N_NODES / 64)
#define DYN_LDS 34816         // gemm branch: Bh+Bl (bin branch uses none)

typedef short short8 __attribute__((ext_vector_type(8)));
typedef float f32x4 __attribute__((ext_vector_type(4)));

__device__ __forceinline__ unsigned short f2bf_rtn(float f) {
    unsigned int u = __float_as_uint(f);
    u += 0x7fffu + ((u >> 16) & 1u);  // round-to-nearest-even
    return (unsigned short)(u >> 16);
}
__device__ __forceinline__ float bf2f(unsigned short h) {
    return __uint_as_float((unsigned)h << 16);
}

// ---------------- fused_prep: [0,NBINB) bin edges | [NBINB,..) MFMA GEMM ------
// Bin: direct global-atomic slab binning, packed = (local_d<<17)|src.
// GEMM: h = x @ W^T via split bf16 (xh*(wh+wl)); A-fragments loaded straight
// from global into registers (no X LDS); W converted fp32->bf16 hi/lo inline.
__global__ __launch_bounds__(256) void fused_prep(
        const int* __restrict__ src, const int* __restrict__ dst,
        const float* __restrict__ x, const float* __restrict__ W,
        const float* __restrict__ a_l, const float* __restrict__ a_r,
        unsigned* __restrict__ gcount, unsigned* __restrict__ binned,
        unsigned short* __restrict__ hb, float* __restrict__ e_l,
        float* __restrict__ e_r) {
    extern __shared__ __align__(16) char smem[];
    int tid = threadIdx.x;

    if (blockIdx.x < NBINB) {
        // ---------------- binning branch: no LDS, no barriers ----------------
        int base = blockIdx.x * BEPB;
        const int4* d4 = (const int4*)dst;
        const int4* s4 = (const int4*)src;
        int i40 = base >> 2;
        for (int it = 0; it < 16; ++it) {
            int i4 = i40 + it * 256 + tid;
            if (i4 * 4 < N_EDGES) {
                int4 dv = d4[i4];
                int4 sv = s4[i4];
#define PUT(dd, ss)                                                          \
                {                                                            \
                    int b = (dd) >> 5;                                       \
                    unsigned r = atomicAdd(&gcount[b], 1u);                  \
                    if (r < ECAP)                                            \
                        binned[(size_t)b * ECAP + r] =                       \
                            ((unsigned)((dd) & 31) << 17) | (unsigned)(ss);  \
                }
                PUT(dv.x, sv.x) PUT(dv.y, sv.y) PUT(dv.z, sv.z) PUT(dv.w, sv.w)
#undef PUT
            }
        }
        return;
    }

    // ---------------- GEMM branch ----------------
    unsigned short (*Bh)[136] = (unsigned short(*)[136])smem;
    unsigned short (*Bl)[136] = (unsigned short(*)[136])(smem + 17408);
    int lane = tid & 63, wid = tid >> 6;
    int p = lane & 15, g = lane >> 4;
    int row0 = (blockIdx.x - NBINB) * 64;
    int n = N_NODES;

    // A fragments: lane owns row (row0 + wid*16 + p), k-cols kc*32+g*8..+8.
    // 8 coalesced float4 loads issued up front; convert to bf16-hi in regs.
    int arow = row0 + wid * 16 + p;
    int arow_c = min(arow, n - 1);
    const float4* X4 = (const float4*)x;
    float4 xa0[4], xa1[4];
#pragma unroll
    for (int kc = 0; kc < 4; ++kc) {
        size_t bi = (size_t)arow_c * 32 + kc * 8 + g * 2;
        xa0[kc] = X4[bi];
        xa1[kc] = X4[bi + 1];
    }
    short8 ah[4];
#pragma unroll
    for (int kc = 0; kc < 4; ++kc) {
        short8 a;
        a[0] = (short)f2bf_rtn(xa0[kc].x);
        a[1] = (short)f2bf_rtn(xa0[kc].y);
        a[2] = (short)f2bf_rtn(xa0[kc].z);
        a[3] = (short)f2bf_rtn(xa0[kc].w);
        a[4] = (short)f2bf_rtn(xa1[kc].x);
        a[5] = (short)f2bf_rtn(xa1[kc].y);
        a[6] = (short)f2bf_rtn(xa1[kc].z);
        a[7] = (short)f2bf_rtn(xa1[kc].w);
        ah[kc] = a;
    }

    f32x4 acc[2][4];
#pragma unroll
    for (int hf = 0; hf < 2; ++hf)
#pragma unroll
        for (int ct = 0; ct < 4; ++ct) acc[hf][ct] = (f32x4)(0.f);

    const float4* W4 = (const float4*)W;

#pragma unroll
    for (int hf = 0; hf < 2; ++hf) {
        __syncthreads();  // protect Bh/Bl reuse across hf halves
        // stage W half rows hf*64..+64 fp32 -> bf16 hi/lo in LDS
        for (int q = 0; q < 8; ++q) {
            int idx = q * 256 + tid;
            int r = idx >> 5, c4 = idx & 31;
            float4 v = W4[((size_t)(hf * 64 + r)) * 32 + c4];
            ushort4 hh, ll;
            hh.x = f2bf_rtn(v.x); ll.x = f2bf_rtn(v.x - bf2f(hh.x));
            hh.y = f2bf_rtn(v.y); ll.y = f2bf_rtn(v.y - bf2f(hh.y));
            hh.z = f2bf_rtn(v.z); ll.z = f2bf_rtn(v.z - bf2f(hh.z));
            hh.w = f2bf_rtn(v.w); ll.w = f2bf_rtn(v.w - bf2f(hh.w));
            *(ushort4*)&Bh[r][c4 * 4] = hh;
            *(ushort4*)&Bl[r][c4 * 4] = ll;
        }
        __syncthreads();

#pragma unroll
        for (int kc = 0; kc < 4; ++kc) {
            int cb = kc * 32 + g * 8;
#pragma unroll
            for (int ct = 0; ct < 4; ++ct) {
                short8 bh = *(const short8*)&Bh[ct * 16 + p][cb];
                short8 bl = *(const short8*)&Bl[ct * 16 + p][cb];
                acc[hf][ct] = __builtin_amdgcn_mfma_f32_16x16x32_bf16(ah[kc], bh, acc[hf][ct], 0, 0, 0);
                acc[hf][ct] = __builtin_amdgcn_mfma_f32_16x16x32_bf16(ah[kc], bl, acc[hf][ct], 0, 0, 0);
            }
        }
    }

    // epilogue: lane holds D[g*4+i][hf*64+ct*16+p]
    float al8[2][4], ar8[2][4];
#pragma unroll
    for (int hf = 0; hf < 2; ++hf)
#pragma unroll
        for (int ct = 0; ct < 4; ++ct) {
            al8[hf][ct] = a_l[hf * 64 + ct * 16 + p];
            ar8[hf][ct] = a_r[hf * 64 + ct * 16 + p];
        }
#pragma unroll
    for (int i = 0; i < 4; ++i) {
        int gr = row0 + wid * 16 + g * 4 + i;
        bool ok = gr < n;
        float pl = 0.f, pr = 0.f;
        if (ok) {
#pragma unroll
            for (int hf = 0; hf < 2; ++hf)
#pragma unroll
                for (int ct = 0; ct < 4; ++ct) {
                    float v = acc[hf][ct][i];
                    hb[(size_t)gr * 128 + hf * 64 + ct * 16 + p] = f2bf_rtn(v);
                    pl += v * al8[hf][ct];
                    pr += v * ar8[hf][ct];
                }
        }
#pragma unroll
        for (int o = 8; o; o >>= 1) {
            pl += __shfl_xor(pl, o);
            pr += __shfl_xor(pr, o);
        }
        if (ok && p == 0) { e_l[gr] = pl; e_r[gr] = pr; }
    }
}

// ---------------- fused: LDS counting sort + per-node register aggregation ----
// 1 block / 32 nodes. Max-free softmax (|logit| <= ~13 -> exp safe in fp32).
__global__ __launch_bounds__(256) void bucket_fused(
        const unsigned short* __restrict__ hb, const float* __restrict__ e_l,
        const float* __restrict__ e_r, const unsigned* __restrict__ gcount,
        const unsigned* __restrict__ binned, float* __restrict__ out) {
    __shared__ unsigned es[ECAP];          // packed (ld<<17)|src
    __shared__ float    ee[ECAP];          // exp(leaky(logit))
    __shared__ unsigned short sidx[ECAP];  // per-node sorted permutation
    __shared__ unsigned cntl[BK];
    __shared__ unsigned startl[BK];
    __shared__ unsigned curl[BK];
    __shared__ float    erl[BK];
    __shared__ int   lds_s[4][64];
    __shared__ float lds_e[4][64];

    int tid = threadIdx.x, lane = tid & 63, w = tid >> 6;
    int g = lane >> 4, p = lane & 15;
    int b = blockIdx.x, d0 = b * BK;
    size_t rs = (size_t)b * ECAP;
    int cnt = min((int)gcount[b], ECAP);

    if (tid < BK) {
        int d = d0 + tid;
        erl[tid] = (d < N_NODES) ? e_r[d] : 0.f;
        cntl[tid] = 0u;
    }
    __syncthreads();

#define ACC8(hv, xe)                                                        \
    acc[0] += xe * __uint_as_float(hv.x << 16);                             \
    acc[1] += xe * __uint_as_float(hv.x & 0xffff0000u);                     \
    acc[2] += xe * __uint_as_float(hv.y << 16);                             \
    acc[3] += xe * __uint_as_float(hv.y & 0xffff0000u);                     \
    acc[4] += xe * __uint_as_float(hv.z << 16);                             \
    acc[5] += xe * __uint_as_float(hv.z & 0xffff0000u);                     \
    acc[6] += xe * __uint_as_float(hv.w << 16);                             \
    acc[7] += xe * __uint_as_float(hv.w & 0xffff0000u);

    // P1: stage + leaky logit + exp + per-node count
    for (int i = tid; i < cnt; i += 256) {
        unsigned v = binned[rs + i];
        unsigned ld = v >> 17;
        float e = e_l[v & 0x1ffffu] + erl[ld];
        e = (e >= 0.f) ? e : NEG_SLOPE_F * e;
        es[i] = v;
        ee[i] = __expf(e);
        atomicAdd(&cntl[ld], 1u);
    }
    __syncthreads();
    // P2: exclusive scan of 32 counts (first wave)
    if (tid < BK) {
        unsigned c = cntl[tid];
        unsigned inc = c;
#pragma unroll
        for (int o = 1; o < BK; o <<= 1) {
            unsigned nv = __shfl_up(inc, o);
            if (lane >= o) inc += nv;
        }
        startl[tid] = inc - c;
        curl[tid] = inc - c;
    }
    __syncthreads();
    // P3: in-LDS scatter to per-node order
    for (int i = tid; i < cnt; i += 256) {
        unsigned ld = es[i] >> 17;
        unsigned pos = atomicAdd(&curl[ld], 1u);
        sidx[pos] = (unsigned short)i;
    }
    __syncthreads();
    // P4: per-node single-pass aggregation; wave w handles ld = 4k + w
    for (int k = 0; k < BK / 4; ++k) {
        int ld = (k << 2) | w;
        int start = (int)startl[ld];
        int deg = (int)cntl[ld];

        float denom = 0.f;
        float acc[8];
#pragma unroll
        for (int q = 0; q < 8; ++q) acc[q] = 0.f;
        for (int b2 = 0; b2 < deg; b2 += 64) {
            int kk = b2 + lane;
            bool valid = kk < deg;
            int i = valid ? sidx[start + kk] : 0;
            float ex = valid ? ee[i] : 0.f;
            denom += ex;
            lds_s[w][lane] = valid ? (int)(es[i] & 0x1ffffu) : 0;
            lds_e[w][lane] = ex;
            asm volatile("s_waitcnt lgkmcnt(0)" ::: "memory");
            int c2 = min(64, deg - b2);
            int nst = (c2 + 3) >> 2;
            int u = 0;
            for (; u + 4 <= nst; u += 4) {
                int j0 = u * 4 + g;
                int s0 = lds_s[w][j0];       float x0 = lds_e[w][j0];
                int s1 = lds_s[w][j0 + 4];   float x1 = lds_e[w][j0 + 4];
                int s2 = lds_s[w][j0 + 8];   float x2 = lds_e[w][j0 + 8];
                int s3 = lds_s[w][j0 + 12];  float x3 = lds_e[w][j0 + 12];
                uint4 h0 = *(const uint4*)&hb[(size_t)s0 * 128 + p * 8];
                uint4 h1 = *(const uint4*)&hb[(size_t)s1 * 128 + p * 8];
                uint4 h2 = *(const uint4*)&hb[(size_t)s2 * 128 + p * 8];
                uint4 h3 = *(const uint4*)&hb[(size_t)s3 * 128 + p * 8];
                ACC8(h0, x0) ACC8(h1, x1) ACC8(h2, x2) ACC8(h3, x3)
            }
            for (; u < nst; ++u) {
                int j = u * 4 + g;
                int sj = lds_s[w][j];
                float xj = lds_e[w][j];
                uint4 hv = *(const uint4*)&hb[(size_t)sj * 128 + p * 8];
                ACC8(hv, xj)
            }
        }
#pragma unroll
        for (int q = 0; q < 8; ++q) {
            acc[q] += __shfl_xor(acc[q], 16);
            acc[q] += __shfl_xor(acc[q], 32);
        }
#pragma unroll
        for (int o = 32; o; o >>= 1) denom += __shfl_xor(denom, o);
        float inv = 1.f / fmaxf(denom, 1e-38f);
        int d = d0 + ld;
        if (g == 0 && d < N_NODES) {
            f32x4 o0 = {acc[0] * inv, acc[1] * inv, acc[2] * inv, acc[3] * inv};
            f32x4 o1 = {acc[4] * inv, acc[5] * inv, acc[6] * inv, acc[7] * inv};
            __builtin_nontemporal_store(o0, (f32x4*)&out[(size_t)d * 128 + p * 8]);
            __builtin_nontemporal_store(o1, (f32x4*)&out[(size_t)d * 128 + p * 8 + 4]);
        }
    }
#undef ACC8
}

extern "C" void kernel_launch(void* const* d_in, const int* in_sizes, int n_in,
                              void* d_out, int out_size, void* d_ws, size_t ws_size,
                              hipStream_t stream) {
    const float* x   = (const float*)d_in[0];
    const int*   src = (const int*)d_in[1];
    const int*   dst = (const int*)d_in[2];
    const float* W   = (const float*)d_in[3];
    const float* a_l = (const float*)d_in[4];
    const float* a_r = (const float*)d_in[5];
    float* out = (float*)d_out;

    char* ws = (char*)d_ws;
    unsigned short* hb = (unsigned short*)ws; ws += (size_t)N_NODES * D * 2;
    float*    e_l    = (float*)ws;    ws += (size_t)N_NODES * 4;
    float*    e_r    = (float*)ws;    ws += (size_t)N_NODES * 4;
    unsigned* gcount = (unsigned*)ws; ws += (size_t)NB3 * 4;
    unsigned* binned = (unsigned*)ws; ws += (size_t)NB3 * ECAP * 4;

    hipMemsetAsync(gcount, 0, (size_t)NB3 * 4, stream);

    fused_prep<<<NBINB + NGEMM, 256, DYN_LDS, stream>>>(
        src, dst, x, W, a_l, a_r, gcount, binned, hb, e_l, e_r);
    bucket_fused<<<NB3, 256, 0, stream>>>(hb, e_l, e_r, gcount, binned, out);
}

// Round 14
// 117.387 us; speedup vs baseline: 1.8800x; 1.8800x over previous
//
#include <hip/hip_runtime.h>
#include <math.h>

#define N_NODES 100000
#define N_EDGES 1600000
#define D 128
#define NEG_SLOPE_F 0.2f
#define BK 32                 // nodes per bucket
#define NB3 3125              // N_NODES / 32 (exact)
#define NHW 1563              // ceil(NB3 / 2) packed u16 histogram words
#define ECAP 1024             // slab capacity per bucket (avg 512, max ~610)
#define BEPB 16384            // edges per block, bin branch
#define NBINB 98              // ceil(N_EDGES / BEPB)
#define NGEMM 1563            // ceil(N_NODES / 64)
#define DYN_LDS 18816         // max(bin 6256+12500, gemm 2*32*136*2=17408)

typedef short short8 __attribute__((ext_vector_type(8)));
typedef float f32x4 __attribute__((ext_vector_type(4)));

__device__ __forceinline__ unsigned short f2bf_rtn(float f) {
    unsigned int u = __float_as_uint(f);
    u += 0x7fffu + ((u >> 16) & 1u);  // round-to-nearest-even
    return (unsigned short)(u >> 16);
}
__device__ __forceinline__ float bf2f(unsigned short h) {
    return __uint_as_float((unsigned)h << 16);
}

// ---------------- fused_prep: [0,NBINB) bin edges | [NBINB,..) MFMA GEMM ------
// Bin: LDS 3-phase histogram (packed 2xu16/word) -> block reservation -> slab
// scatter; packed edge = (local_d<<17)|src.
// GEMM: h = x @ W^T via split bf16 (xh*(wh+wl)); A-fragments global->reg;
// W staged fp32->bf16 hi/lo in four 32-row quarters (LDS 17.4 KB).
__global__ __launch_bounds__(256) void fused_prep(
        const int* __restrict__ src, const int* __restrict__ dst,
        const float* __restrict__ x, const float* __restrict__ W,
        const float* __restrict__ a_l, const float* __restrict__ a_r,
        unsigned* __restrict__ gcount, unsigned* __restrict__ binned,
        unsigned short* __restrict__ hb, float* __restrict__ e_l,
        float* __restrict__ e_r) {
    extern __shared__ __align__(16) char smem[];
    int tid = threadIdx.x;

    if (blockIdx.x < NBINB) {
        // ---------------- binning branch ----------------
        unsigned* histp  = (unsigned*)smem;            // NHW packed u16 pairs
        unsigned* startb = (unsigned*)(smem + 6256);   // NB3
        for (int i = tid; i < NHW; i += 256) histp[i] = 0;
        __syncthreads();
        int base = blockIdx.x * BEPB;
        const int4* d4 = (const int4*)dst;
        const int4* s4 = (const int4*)src;
        int i40 = base >> 2;
        // P1: count (packed halfword atomics)
        for (int it = 0; it < 16; ++it) {
            int i4 = i40 + it * 256 + tid;
            if (i4 * 4 < N_EDGES) {
                int4 v = d4[i4];
#define CNT(dd) { int b = (dd) >> 5; atomicAdd(&histp[b >> 1], (b & 1) ? 65536u : 1u); }
                CNT(v.x) CNT(v.y) CNT(v.z) CNT(v.w)
#undef CNT
            }
        }
        __syncthreads();
        // P2: one global reservation per (block,bucket)
        for (int b = tid; b < NB3; b += 256) {
            unsigned c = (histp[b >> 1] >> ((b & 1) * 16)) & 0xffffu;
            startb[b] = c ? atomicAdd(&gcount[b], c) : 0u;
        }
        __syncthreads();
        // re-zero histogram -> reuse as scatter cursor
        for (int i = tid; i < NHW; i += 256) histp[i] = 0;
        __syncthreads();
        // P3: scatter into slabs
        for (int it = 0; it < 16; ++it) {
            int i4 = i40 + it * 256 + tid;
            if (i4 * 4 < N_EDGES) {
                int4 dv = d4[i4];
                int4 sv = s4[i4];
#define PUT(dd, ss)                                                          \
                {                                                            \
                    int b = (dd) >> 5;                                       \
                    unsigned old = atomicAdd(&histp[b >> 1],                 \
                                             (b & 1) ? 65536u : 1u);         \
                    unsigned r = startb[b] +                                 \
                                 ((old >> ((b & 1) * 16)) & 0xffffu);        \
                    if (r < ECAP)                                            \
                        binned[(size_t)b * ECAP + r] =                       \
                            ((unsigned)((dd) & 31) << 17) | (unsigned)(ss);  \
                }
                PUT(dv.x, sv.x) PUT(dv.y, sv.y) PUT(dv.z, sv.z) PUT(dv.w, sv.w)
#undef PUT
            }
        }
        return;
    }

    // ---------------- GEMM branch ----------------
    unsigned short (*Bh)[136] = (unsigned short(*)[136])smem;          // 32 rows
    unsigned short (*Bl)[136] = (unsigned short(*)[136])(smem + 8704); // 32 rows
    int lane = tid & 63, wid = tid >> 6;
    int p = lane & 15, g = lane >> 4;
    int row0 = (blockIdx.x - NBINB) * 64;
    int n = N_NODES;

    // A fragments: lane owns row (row0 + wid*16 + p), k-cols kc*32+g*8..+8.
    int arow = row0 + wid * 16 + p;
    int arow_c = min(arow, n - 1);
    const float4* X4 = (const float4*)x;
    float4 xa0[4], xa1[4];
#pragma unroll
    for (int kc = 0; kc < 4; ++kc) {
        size_t bi = (size_t)arow_c * 32 + kc * 8 + g * 2;
        xa0[kc] = X4[bi];
        xa1[kc] = X4[bi + 1];
    }
    short8 ah[4];
#pragma unroll
    for (int kc = 0; kc < 4; ++kc) {
        short8 a;
        a[0] = (short)f2bf_rtn(xa0[kc].x);
        a[1] = (short)f2bf_rtn(xa0[kc].y);
        a[2] = (short)f2bf_rtn(xa0[kc].z);
        a[3] = (short)f2bf_rtn(xa0[kc].w);
        a[4] = (short)f2bf_rtn(xa1[kc].x);
        a[5] = (short)f2bf_rtn(xa1[kc].y);
        a[6] = (short)f2bf_rtn(xa1[kc].z);
        a[7] = (short)f2bf_rtn(xa1[kc].w);
        ah[kc] = a;
    }

    f32x4 acc[4][2];
#pragma unroll
    for (int qt = 0; qt < 4; ++qt)
#pragma unroll
        for (int ct = 0; ct < 2; ++ct) acc[qt][ct] = (f32x4)(0.f);

    const float4* W4 = (const float4*)W;

#pragma unroll
    for (int qt = 0; qt < 4; ++qt) {
        __syncthreads();  // protect Bh/Bl reuse across quarters
        // stage W quarter rows qt*32..+32 fp32 -> bf16 hi/lo (1024 float4)
        for (int q2 = 0; q2 < 4; ++q2) {
            int idx = q2 * 256 + tid;
            int r = idx >> 5, c4 = idx & 31;
            float4 v = W4[((size_t)(qt * 32 + r)) * 32 + c4];
            ushort4 hh, ll;
            hh.x = f2bf_rtn(v.x); ll.x = f2bf_rtn(v.x - bf2f(hh.x));
            hh.y = f2bf_rtn(v.y); ll.y = f2bf_rtn(v.y - bf2f(hh.y));
            hh.z = f2bf_rtn(v.z); ll.z = f2bf_rtn(v.z - bf2f(hh.z));
            hh.w = f2bf_rtn(v.w); ll.w = f2bf_rtn(v.w - bf2f(hh.w));
            *(ushort4*)&Bh[r][c4 * 4] = hh;
            *(ushort4*)&Bl[r][c4 * 4] = ll;
        }
        __syncthreads();

#pragma unroll
        for (int kc = 0; kc < 4; ++kc) {
            int cb = kc * 32 + g * 8;
#pragma unroll
            for (int ct = 0; ct < 2; ++ct) {
                short8 bh = *(const short8*)&Bh[ct * 16 + p][cb];
                short8 bl = *(const short8*)&Bl[ct * 16 + p][cb];
                acc[qt][ct] = __builtin_amdgcn_mfma_f32_16x16x32_bf16(ah[kc], bh, acc[qt][ct], 0, 0, 0);
                acc[qt][ct] = __builtin_amdgcn_mfma_f32_16x16x32_bf16(ah[kc], bl, acc[qt][ct], 0, 0, 0);
            }
        }
    }

    // epilogue: lane holds D[g*4+i][qt*32+ct*16+p]
    float al8[4][2], ar8[4][2];
#pragma unroll
    for (int qt = 0; qt < 4; ++qt)
#pragma unroll
        for (int ct = 0; ct < 2; ++ct) {
            al8[qt][ct] = a_l[qt * 32 + ct * 16 + p];
            ar8[qt][ct] = a_r[qt * 32 + ct * 16 + p];
        }
#pragma unroll
    for (int i = 0; i < 4; ++i) {
        int gr = row0 + wid * 16 + g * 4 + i;
        bool ok = gr < n;
        float pl = 0.f, pr = 0.f;
        if (ok) {
#pragma unroll
            for (int qt = 0; qt < 4; ++qt)
#pragma unroll
                for (int ct = 0; ct < 2; ++ct) {
                    float v = acc[qt][ct][i];
                    hb[(size_t)gr * 128 + qt * 32 + ct * 16 + p] = f2bf_rtn(v);
                    pl += v * al8[qt][ct];
                    pr += v * ar8[qt][ct];
                }
        }
#pragma unroll
        for (int o = 8; o; o >>= 1) {
            pl += __shfl_xor(pl, o);
            pr += __shfl_xor(pr, o);
        }
        if (ok && p == 0) { e_l[gr] = pl; e_r[gr] = pr; }
    }
}

// ---------------- fused: LDS counting sort + per-node register aggregation ----
// 1 block / 32 nodes. Max-free softmax (|logit| <= ~13 -> exp safe in fp32).
__global__ __launch_bounds__(256) void bucket_fused(
        const unsigned short* __restrict__ hb, const float* __restrict__ e_l,
        const float* __restrict__ e_r, const unsigned* __restrict__ gcount,
        const unsigned* __restrict__ binned, float* __restrict__ out) {
    __shared__ unsigned es[ECAP];          // packed (ld<<17)|src
    __shared__ float    ee[ECAP];          // exp(leaky(logit))
    __shared__ unsigned short sidx[ECAP];  // per-node sorted permutation
    __shared__ unsigned cntl[BK];
    __shared__ unsigned startl[BK];
    __shared__ unsigned curl[BK];
    __shared__ float    erl[BK];
    __shared__ int   lds_s[4][64];
    __shared__ float lds_e[4][64];

    int tid = threadIdx.x, lane = tid & 63, w = tid >> 6;
    int g = lane >> 4, p = lane & 15;
    int b = blockIdx.x, d0 = b * BK;
    size_t rs = (size_t)b * ECAP;
    int cnt = min((int)gcount[b], ECAP);

    if (tid < BK) {
        int d = d0 + tid;
        erl[tid] = (d < N_NODES) ? e_r[d] : 0.f;
        cntl[tid] = 0u;
    }
    __syncthreads();

#define ACC8(hv, xe)                                                        \
    acc[0] += xe * __uint_as_float(hv.x << 16);                             \
    acc[1] += xe * __uint_as_float(hv.x & 0xffff0000u);                     \
    acc[2] += xe * __uint_as_float(hv.y << 16);                             \
    acc[3] += xe * __uint_as_float(hv.y & 0xffff0000u);                     \
    acc[4] += xe * __uint_as_float(hv.z << 16);                             \
    acc[5] += xe * __uint_as_float(hv.z & 0xffff0000u);                     \
    acc[6] += xe * __uint_as_float(hv.w << 16);                             \
    acc[7] += xe * __uint_as_float(hv.w & 0xffff0000u);

    // P1: stage + leaky logit + exp + per-node count
    for (int i = tid; i < cnt; i += 256) {
        unsigned v = binned[rs + i];
        unsigned ld = v >> 17;
        float e = e_l[v & 0x1ffffu] + erl[ld];
        e = (e >= 0.f) ? e : NEG_SLOPE_F * e;
        es[i] = v;
        ee[i] = __expf(e);
        atomicAdd(&cntl[ld], 1u);
    }
    __syncthreads();
    // P2: exclusive scan of 32 counts (first wave)
    if (tid < BK) {
        unsigned c = cntl[tid];
        unsigned inc = c;
#pragma unroll
        for (int o = 1; o < BK; o <<= 1) {
            unsigned nv = __shfl_up(inc, o);
            if (lane >= o) inc += nv;
        }
        startl[tid] = inc - c;
        curl[tid] = inc - c;
    }
    __syncthreads();
    // P3: in-LDS scatter to per-node order
    for (int i = tid; i < cnt; i += 256) {
        unsigned ld = es[i] >> 17;
        unsigned pos = atomicAdd(&curl[ld], 1u);
        sidx[pos] = (unsigned short)i;
    }
    __syncthreads();
    // P4: per-node single-pass aggregation; wave w handles ld = 4k + w
    for (int k = 0; k < BK / 4; ++k) {
        int ld = (k << 2) | w;
        int start = (int)startl[ld];
        int deg = (int)cntl[ld];

        float denom = 0.f;
        float acc[8];
#pragma unroll
        for (int q = 0; q < 8; ++q) acc[q] = 0.f;
        for (int b2 = 0; b2 < deg; b2 += 64) {
            int kk = b2 + lane;
            bool valid = kk < deg;
            int i = valid ? sidx[start + kk] : 0;
            float ex = valid ? ee[i] : 0.f;
            denom += ex;
            lds_s[w][lane] = valid ? (int)(es[i] & 0x1ffffu) : 0;
            lds_e[w][lane] = ex;
            asm volatile("s_waitcnt lgkmcnt(0)" ::: "memory");
            int c2 = min(64, deg - b2);
            int nst = (c2 + 3) >> 2;
            int u = 0;
            for (; u + 4 <= nst; u += 4) {
                int j0 = u * 4 + g;
                int s0 = lds_s[w][j0];       float x0 = lds_e[w][j0];
                int s1 = lds_s[w][j0 + 4];   float x1 = lds_e[w][j0 + 4];
                int s2 = lds_s[w][j0 + 8];   float x2 = lds_e[w][j0 + 8];
                int s3 = lds_s[w][j0 + 12];  float x3 = lds_e[w][j0 + 12];
                uint4 h0 = *(const uint4*)&hb[(size_t)s0 * 128 + p * 8];
                uint4 h1 = *(const uint4*)&hb[(size_t)s1 * 128 + p * 8];
                uint4 h2 = *(const uint4*)&hb[(size_t)s2 * 128 + p * 8];
                uint4 h3 = *(const uint4*)&hb[(size_t)s3 * 128 + p * 8];
                ACC8(h0, x0) ACC8(h1, x1) ACC8(h2, x2) ACC8(h3, x3)
            }
            for (; u < nst; ++u) {
                int j = u * 4 + g;
                int sj = lds_s[w][j];
                float xj = lds_e[w][j];
                uint4 hv = *(const uint4*)&hb[(size_t)sj * 128 + p * 8];
                ACC8(hv, xj)
            }
        }
#pragma unroll
        for (int q = 0; q < 8; ++q) {
            acc[q] += __shfl_xor(acc[q], 16);
            acc[q] += __shfl_xor(acc[q], 32);
        }
#pragma unroll
        for (int o = 32; o; o >>= 1) denom += __shfl_xor(denom, o);
        float inv = 1.f / fmaxf(denom, 1e-38f);
        int d = d0 + ld;
        if (g == 0 && d < N_NODES) {
            f32x4 o0 = {acc[0] * inv, acc[1] * inv, acc[2] * inv, acc[3] * inv};
            f32x4 o1 = {acc[4] * inv, acc[5] * inv, acc[6] * inv, acc[7] * inv};
            __builtin_nontemporal_store(o0, (f32x4*)&out[(size_t)d * 128 + p * 8]);
            __builtin_nontemporal_store(o1, (f32x4*)&out[(size_t)d * 128 + p * 8 + 4]);
        }
    }
#undef ACC8
}

extern "C" void kernel_launch(void* const* d_in, const int* in_sizes, int n_in,
                              void* d_out, int out_size, void* d_ws, size_t ws_size,
                              hipStream_t stream) {
    const float* x   = (const float*)d_in[0];
    const int*   src = (const int*)d_in[1];
    const int*   dst = (const int*)d_in[2];
    const float* W   = (const float*)d_in[3];
    const float* a_l = (const float*)d_in[4];
    const float* a_r = (const float*)d_in[5];
    float* out = (float*)d_out;

    char* ws = (char*)d_ws;
    unsigned short* hb = (unsigned short*)ws; ws += (size_t)N_NODES * D * 2;
    float*    e_l    = (float*)ws;    ws += (size_t)N_NODES * 4;
    float*    e_r    = (float*)ws;    ws += (size_t)N_NODES * 4;
    unsigned* gcount = (unsigned*)ws; ws += (size_t)NB3 * 4;
    unsigned* binned = (unsigned*)ws; ws += (size_t)NB3 * ECAP * 4;

    hipMemsetAsync(gcount, 0, (size_t)NB3 * 4, stream);

    fused_prep<<<NBINB + NGEMM, 256, DYN_LDS, stream>>>(
        src, dst, x, W, a_l, a_r, gcount, binned, hb, e_l, e_r);
    bucket_fused<<<NB3, 256, 0, stream>>>(hb, e_l, e_r, gcount, binned, out);
}

// Round 15
// 112.187 us; speedup vs baseline: 1.9671x; 1.0464x over previous
//
#include <hip/hip_runtime.h>
#include <math.h>

#define N_NODES 100000
#define N_EDGES 1600000
#define D 128
#define NEG_SLOPE_F 0.2f
#define BK 32                 // nodes per bucket
#define NB3 3125              // N_NODES / 32 (exact)
#define NHW 1563              // ceil(NB3 / 2) packed u16 histogram words
#define ECAP 1024             // slab capacity per bucket (avg 512, max ~610)
#define BEPB 8192             // edges per block, bin branch (R15: halved)
#define BITERS (BEPB / 1024)  // int4 iterations per bin block
#define NBINB 196             // ceil(N_EDGES / BEPB)
#define NGEMM 1563            // ceil(N_NODES / 64)
#define DYN_LDS 18816         // max(bin 6256+12500, gemm 2*32*136*2=17408)

typedef short short8 __attribute__((ext_vector_type(8)));
typedef float f32x4 __attribute__((ext_vector_type(4)));

__device__ __forceinline__ unsigned short f2bf_rtn(float f) {
    unsigned int u = __float_as_uint(f);
    u += 0x7fffu + ((u >> 16) & 1u);  // round-to-nearest-even
    return (unsigned short)(u >> 16);
}
__device__ __forceinline__ float bf2f(unsigned short h) {
    return __uint_as_float((unsigned)h << 16);
}

// ---------------- fused_prep: [0,NBINB) bin edges | [NBINB,..) MFMA GEMM ------
// Bin: LDS 3-phase histogram (packed 2xu16/word) -> block reservation -> slab
// scatter; packed edge = (local_d<<17)|src.
// GEMM: h = x @ W^T via split bf16 (xh*(wh+wl)); A-fragments global->reg;
// W staged fp32->bf16 hi/lo in four 32-row quarters (LDS 17.4 KB).
__global__ __launch_bounds__(256) void fused_prep(
        const int* __restrict__ src, const int* __restrict__ dst,
        const float* __restrict__ x, const float* __restrict__ W,
        const float* __restrict__ a_l, const float* __restrict__ a_r,
        unsigned* __restrict__ gcount, unsigned* __restrict__ binned,
        unsigned short* __restrict__ hb, float* __restrict__ e_l,
        float* __restrict__ e_r) {
    extern __shared__ __align__(16) char smem[];
    int tid = threadIdx.x;

    if (blockIdx.x < NBINB) {
        // ---------------- binning branch ----------------
        unsigned* histp  = (unsigned*)smem;            // NHW packed u16 pairs
        unsigned* startb = (unsigned*)(smem + 6256);   // NB3
        for (int i = tid; i < NHW; i += 256) histp[i] = 0;
        __syncthreads();
        int base = blockIdx.x * BEPB;
        const int4* d4 = (const int4*)dst;
        const int4* s4 = (const int4*)src;
        int i40 = base >> 2;
        // P1: count (packed halfword atomics)
        for (int it = 0; it < BITERS; ++it) {
            int i4 = i40 + it * 256 + tid;
            if (i4 * 4 < N_EDGES) {
                int4 v = d4[i4];
#define CNT(dd) { int b = (dd) >> 5; atomicAdd(&histp[b >> 1], (b & 1) ? 65536u : 1u); }
                CNT(v.x) CNT(v.y) CNT(v.z) CNT(v.w)
#undef CNT
            }
        }
        __syncthreads();
        // P2: one global reservation per (block,bucket)
        for (int b = tid; b < NB3; b += 256) {
            unsigned c = (histp[b >> 1] >> ((b & 1) * 16)) & 0xffffu;
            startb[b] = c ? atomicAdd(&gcount[b], c) : 0u;
        }
        __syncthreads();
        // re-zero histogram -> reuse as scatter cursor
        for (int i = tid; i < NHW; i += 256) histp[i] = 0;
        __syncthreads();
        // P3: scatter into slabs
        for (int it = 0; it < BITERS; ++it) {
            int i4 = i40 + it * 256 + tid;
            if (i4 * 4 < N_EDGES) {
                int4 dv = d4[i4];
                int4 sv = s4[i4];
#define PUT(dd, ss)                                                          \
                {                                                            \
                    int b = (dd) >> 5;                                       \
                    unsigned old = atomicAdd(&histp[b >> 1],                 \
                                             (b & 1) ? 65536u : 1u);         \
                    unsigned r = startb[b] +                                 \
                                 ((old >> ((b & 1) * 16)) & 0xffffu);        \
                    if (r < ECAP)                                            \
                        binned[(size_t)b * ECAP + r] =                       \
                            ((unsigned)((dd) & 31) << 17) | (unsigned)(ss);  \
                }
                PUT(dv.x, sv.x) PUT(dv.y, sv.y) PUT(dv.z, sv.z) PUT(dv.w, sv.w)
#undef PUT
            }
        }
        return;
    }

    // ---------------- GEMM branch ----------------
    unsigned short (*Bh)[136] = (unsigned short(*)[136])smem;          // 32 rows
    unsigned short (*Bl)[136] = (unsigned short(*)[136])(smem + 8704); // 32 rows
    int lane = tid & 63, wid = tid >> 6;
    int p = lane & 15, g = lane >> 4;
    int row0 = (blockIdx.x - NBINB) * 64;
    int n = N_NODES;

    // A fragments: lane owns row (row0 + wid*16 + p), k-cols kc*32+g*8..+8.
    int arow = row0 + wid * 16 + p;
    int arow_c = min(arow, n - 1);
    const float4* X4 = (const float4*)x;
    float4 xa0[4], xa1[4];
#pragma unroll
    for (int kc = 0; kc < 4; ++kc) {
        size_t bi = (size_t)arow_c * 32 + kc * 8 + g * 2;
        xa0[kc] = X4[bi];
        xa1[kc] = X4[bi + 1];
    }
    short8 ah[4];
#pragma unroll
    for (int kc = 0; kc < 4; ++kc) {
        short8 a;
        a[0] = (short)f2bf_rtn(xa0[kc].x);
        a[1] = (short)f2bf_rtn(xa0[kc].y);
        a[2] = (short)f2bf_rtn(xa0[kc].z);
        a[3] = (short)f2bf_rtn(xa0[kc].w);
        a[4] = (short)f2bf_rtn(xa1[kc].x);
        a[5] = (short)f2bf_rtn(xa1[kc].y);
        a[6] = (short)f2bf_rtn(xa1[kc].z);
        a[7] = (short)f2bf_rtn(xa1[kc].w);
        ah[kc] = a;
    }

    f32x4 acc[4][2];
#pragma unroll
    for (int qt = 0; qt < 4; ++qt)
#pragma unroll
        for (int ct = 0; ct < 2; ++ct) acc[qt][ct] = (f32x4)(0.f);

    const float4* W4 = (const float4*)W;

#pragma unroll
    for (int qt = 0; qt < 4; ++qt) {
        __syncthreads();  // protect Bh/Bl reuse across quarters
        // stage W quarter rows qt*32..+32 fp32 -> bf16 hi/lo (1024 float4)
        for (int q2 = 0; q2 < 4; ++q2) {
            int idx = q2 * 256 + tid;
            int r = idx >> 5, c4 = idx & 31;
            float4 v = W4[((size_t)(qt * 32 + r)) * 32 + c4];
            ushort4 hh, ll;
            hh.x = f2bf_rtn(v.x); ll.x = f2bf_rtn(v.x - bf2f(hh.x));
            hh.y = f2bf_rtn(v.y); ll.y = f2bf_rtn(v.y - bf2f(hh.y));
            hh.z = f2bf_rtn(v.z); ll.z = f2bf_rtn(v.z - bf2f(hh.z));
            hh.w = f2bf_rtn(v.w); ll.w = f2bf_rtn(v.w - bf2f(hh.w));
            *(ushort4*)&Bh[r][c4 * 4] = hh;
            *(ushort4*)&Bl[r][c4 * 4] = ll;
        }
        __syncthreads();

#pragma unroll
        for (int kc = 0; kc < 4; ++kc) {
            int cb = kc * 32 + g * 8;
#pragma unroll
            for (int ct = 0; ct < 2; ++ct) {
                short8 bh = *(const short8*)&Bh[ct * 16 + p][cb];
                short8 bl = *(const short8*)&Bl[ct * 16 + p][cb];
                acc[qt][ct] = __builtin_amdgcn_mfma_f32_16x16x32_bf16(ah[kc], bh, acc[qt][ct], 0, 0, 0);
                acc[qt][ct] = __builtin_amdgcn_mfma_f32_16x16x32_bf16(ah[kc], bl, acc[qt][ct], 0, 0, 0);
            }
        }
    }

    // epilogue: lane holds D[g*4+i][qt*32+ct*16+p]
    float al8[4][2], ar8[4][2];
#pragma unroll
    for (int qt = 0; qt < 4; ++qt)
#pragma unroll
        for (int ct = 0; ct < 2; ++ct) {
            al8[qt][ct] = a_l[qt * 32 + ct * 16 + p];
            ar8[qt][ct] = a_r[qt * 32 + ct * 16 + p];
        }
#pragma unroll
    for (int i = 0; i < 4; ++i) {
        int gr = row0 + wid * 16 + g * 4 + i;
        bool ok = gr < n;
        float pl = 0.f, pr = 0.f;
        if (ok) {
#pragma unroll
            for (int qt = 0; qt < 4; ++qt)
#pragma unroll
                for (int ct = 0; ct < 2; ++ct) {
                    float v = acc[qt][ct][i];
                    hb[(size_t)gr * 128 + qt * 32 + ct * 16 + p] = f2bf_rtn(v);
                    pl += v * al8[qt][ct];
                    pr += v * ar8[qt][ct];
                }
        }
#pragma unroll
        for (int o = 8; o; o >>= 1) {
            pl += __shfl_xor(pl, o);
            pr += __shfl_xor(pr, o);
        }
        if (ok && p == 0) { e_l[gr] = pl; e_r[gr] = pr; }
    }
}

// ---------------- fused: LDS counting sort + per-node register aggregation ----
// 1 block / 32 nodes. Max-free softmax (|logit| <= ~13 -> exp safe in fp32).
__global__ __launch_bounds__(256) void bucket_fused(
        const unsigned short* __restrict__ hb, const float* __restrict__ e_l,
        const float* __restrict__ e_r, const unsigned* __restrict__ gcount,
        const unsigned* __restrict__ binned, float* __restrict__ out) {
    __shared__ unsigned es[ECAP];          // packed (ld<<17)|src
    __shared__ float    ee[ECAP];          // exp(leaky(logit))
    __shared__ unsigned short sidx[ECAP];  // per-node sorted permutation
    __shared__ unsigned cntl[BK];
    __shared__ unsigned startl[BK];
    __shared__ unsigned curl[BK];
    __shared__ float    erl[BK];
    __shared__ int   lds_s[4][64];
    __shared__ float lds_e[4][64];

    int tid = threadIdx.x, lane = tid & 63, w = tid >> 6;
    int g = lane >> 4, p = lane & 15;
    int b = blockIdx.x, d0 = b * BK;
    size_t rs = (size_t)b * ECAP;
    int cnt = min((int)gcount[b], ECAP);

    if (tid < BK) {
        int d = d0 + tid;
        erl[tid] = (d < N_NODES) ? e_r[d] : 0.f;
        cntl[tid] = 0u;
    }
    __syncthreads();

#define ACC8(hv, xe)                                                        \
    acc[0] += xe * __uint_as_float(hv.x << 16);                             \
    acc[1] += xe * __uint_as_float(hv.x & 0xffff0000u);                     \
    acc[2] += xe * __uint_as_float(hv.y << 16);                             \
    acc[3] += xe * __uint_as_float(hv.y & 0xffff0000u);                     \
    acc[4] += xe * __uint_as_float(hv.z << 16);                             \
    acc[5] += xe * __uint_as_float(hv.z & 0xffff0000u);                     \
    acc[6] += xe * __uint_as_float(hv.w << 16);                             \
    acc[7] += xe * __uint_as_float(hv.w & 0xffff0000u);

    // P1: stage + leaky logit + exp + per-node count
    for (int i = tid; i < cnt; i += 256) {
        unsigned v = binned[rs + i];
        unsigned ld = v >> 17;
        float e = e_l[v & 0x1ffffu] + erl[ld];
        e = (e >= 0.f) ? e : NEG_SLOPE_F * e;
        es[i] = v;
        ee[i] = __expf(e);
        atomicAdd(&cntl[ld], 1u);
    }
    __syncthreads();
    // P2: exclusive scan of 32 counts (first wave)
    if (tid < BK) {
        unsigned c = cntl[tid];
        unsigned inc = c;
#pragma unroll
        for (int o = 1; o < BK; o <<= 1) {
            unsigned nv = __shfl_up(inc, o);
            if (lane >= o) inc += nv;
        }
        startl[tid] = inc - c;
        curl[tid] = inc - c;
    }
    __syncthreads();
    // P3: in-LDS scatter to per-node order
    for (int i = tid; i < cnt; i += 256) {
        unsigned ld = es[i] >> 17;
        unsigned pos = atomicAdd(&curl[ld], 1u);
        sidx[pos] = (unsigned short)i;
    }
    __syncthreads();
    // P4: per-node single-pass aggregation; wave w handles ld = 4k + w
    for (int k = 0; k < BK / 4; ++k) {
        int ld = (k << 2) | w;
        int start = (int)startl[ld];
        int deg = (int)cntl[ld];

        float denom = 0.f;
        float acc[8];
#pragma unroll
        for (int q = 0; q < 8; ++q) acc[q] = 0.f;
        for (int b2 = 0; b2 < deg; b2 += 64) {
            int kk = b2 + lane;
            bool valid = kk < deg;
            int i = valid ? sidx[start + kk] : 0;
            float ex = valid ? ee[i] : 0.f;
            denom += ex;
            lds_s[w][lane] = valid ? (int)(es[i] & 0x1ffffu) : 0;
            lds_e[w][lane] = ex;
            asm volatile("s_waitcnt lgkmcnt(0)" ::: "memory");
            int c2 = min(64, deg - b2);
            int nst = (c2 + 3) >> 2;
            int u = 0;
            for (; u + 4 <= nst; u += 4) {
                int j0 = u * 4 + g;
                int s0 = lds_s[w][j0];       float x0 = lds_e[w][j0];
                int s1 = lds_s[w][j0 + 4];   float x1 = lds_e[w][j0 + 4];
                int s2 = lds_s[w][j0 + 8];   float x2 = lds_e[w][j0 + 8];
                int s3 = lds_s[w][j0 + 12];  float x3 = lds_e[w][j0 + 12];
                uint4 h0 = *(const uint4*)&hb[(size_t)s0 * 128 + p * 8];
                uint4 h1 = *(const uint4*)&hb[(size_t)s1 * 128 + p * 8];
                uint4 h2 = *(const uint4*)&hb[(size_t)s2 * 128 + p * 8];
                uint4 h3 = *(const uint4*)&hb[(size_t)s3 * 128 + p * 8];
                ACC8(h0, x0) ACC8(h1, x1) ACC8(h2, x2) ACC8(h3, x3)
            }
            for (; u < nst; ++u) {
                int j = u * 4 + g;
                int sj = lds_s[w][j];
                float xj = lds_e[w][j];
                uint4 hv = *(const uint4*)&hb[(size_t)sj * 128 + p * 8];
                ACC8(hv, xj)
            }
        }
#pragma unroll
        for (int q = 0; q < 8; ++q) {
            acc[q] += __shfl_xor(acc[q], 16);
            acc[q] += __shfl_xor(acc[q], 32);
        }
#pragma unroll
        for (int o = 32; o; o >>= 1) denom += __shfl_xor(denom, o);
        float inv = 1.f / fmaxf(denom, 1e-38f);
        int d = d0 + ld;
        if (g == 0 && d < N_NODES) {
            f32x4 o0 = {acc[0] * inv, acc[1] * inv, acc[2] * inv, acc[3] * inv};
            f32x4 o1 = {acc[4] * inv, acc[5] * inv, acc[6] * inv, acc[7] * inv};
            __builtin_nontemporal_store(o0, (f32x4*)&out[(size_t)d * 128 + p * 8]);
            __builtin_nontemporal_store(o1, (f32x4*)&out[(size_t)d * 128 + p * 8 + 4]);
        }
    }
#undef ACC8
}

extern "C" void kernel_launch(void* const* d_in, const int* in_sizes, int n_in,
                              void* d_out, int out_size, void* d_ws, size_t ws_size,
                              hipStream_t stream) {
    const float* x   = (const float*)d_in[0];
    const int*   src = (const int*)d_in[1];
    const int*   dst = (const int*)d_in[2];
    const float* W   = (const float*)d_in[3];
    const float* a_l = (const float*)d_in[4];
    const float* a_r = (const float*)d_in[5];
    float* out = (float*)d_out;

    char* ws = (char*)d_ws;
    unsigned short* hb = (unsigned short*)ws; ws += (size_t)N_NODES * D * 2;
    float*    e_l    = (float*)ws;    ws += (size_t)N_NODES * 4;
    float*    e_r    = (float*)ws;    ws += (size_t)N_NODES * 4;
    unsigned* gcount = (unsigned*)ws; ws += (size_t)NB3 * 4;
    unsigned* binned = (unsigned*)ws; ws += (size_t)NB3 * ECAP * 4;

    hipMemsetAsync(gcount, 0, (size_t)NB3 * 4, stream);

    fused_prep<<<NBINB + NGEMM, 256, DYN_LDS, stream>>>(
        src, dst, x, W, a_l, a_r, gcount, binned, hb, e_l, e_r);
    bucket_fused<<<NB3, 256, 0, stream>>>(hb, e_l, e_r, gcount, binned, out);
}